// Round 12
// baseline (338.277 us; speedup 1.0000x reference)
//
#include <hip/hip_runtime.h>

constexpr int F_IN  = 256;
constexpr int F_OUT = 128;

constexpr int NPSH  = 9;              // 512 nodes per super-bucket
constexpr int NPS   = 1 << NPSH;      // 512
constexpr int EPT   = 16;             // edges/thread in partition pass
constexpr int BATCH = 256 * EPT;      // 4096 edges per block batch
constexpr int CAPS  = 9216;           // slots per segment (avg 8192, +11 sigma)

typedef __attribute__((ext_vector_type(8))) short short8;
typedef __attribute__((ext_vector_type(4))) float f32x4;

// fp32 -> bf16 round-to-nearest-even
__device__ __forceinline__ unsigned short f2bf(float f) {
    unsigned u = __float_as_uint(f);
    u += 0x7fffu + ((u >> 16) & 1u);
    return (unsigned short)(u >> 16);
}

// ---------------------------------------------------------------------------
// Prep: Wt swizzled K-major. Seeds segmented append cursors cursorA[s]=s*CAPS.
// ---------------------------------------------------------------------------
__global__ void prep_wt_kernel(const float* __restrict__ W,
                               unsigned short* __restrict__ Wt,
                               int* __restrict__ cursorA)
{
    int n = blockIdx.x;      // 0..127
    int k = threadIdx.x;     // 0..255
    int ks = k >> 5, kk = k & 31;
    Wt[((ks * F_OUT) + n) * 32 + kk] = f2bf(W[k * F_OUT + n]);
    if (blockIdx.x == 0) cursorA[threadIdx.x] = threadIdx.x * CAPS;
}

// ---------------------------------------------------------------------------
// Stage 1: h = bf16(x @ W) via MFMA 16x16x32 bf16.
// LDS-FREE: B-fragments loaded straight from Wt (64KB, L2-resident,
// per-wave fragment reads are contiguous 1KB => fully coalesced L2 hits).
// No barriers, no LDS -> free compiler pipelining + max occupancy.
// Floor: x-stream 102MB ~ 17us. (If this regresses >61us it will surface
// in the top-5 with counters — self-instrumenting experiment.)
// ---------------------------------------------------------------------------
__global__ __launch_bounds__(256) void gemm_mfma_kernel(
    const float* __restrict__ x, const unsigned short* __restrict__ Wt,
    unsigned short* __restrict__ h, int n_nodes)
{
    const int tid  = threadIdx.x;
    const int wave = tid >> 6;
    const int lane = tid & 63;
    const int m16  = lane & 15;
    const int quad = lane >> 4;
    const int k0q  = quad * 8;
    const int arow = blockIdx.x * 64 + wave * 16 + m16;
    const bool inb = arow < n_nodes;

    f32x4 acc[8];
    #pragma unroll
    for (int t = 0; t < 8; ++t) acc[t] = (f32x4)(0.f);

    float4 a0 = make_float4(0.f,0.f,0.f,0.f), a1 = a0;
    if (inb) {
        a0 = *(const float4*)&x[(long long)arow * F_IN + k0q];
        a1 = *(const float4*)&x[(long long)arow * F_IN + k0q + 4];
    }

    #pragma unroll
    for (int ks = 0; ks < 8; ++ks) {
        // convert current A fragment
        short8 af;
        af[0] = (short)f2bf(a0.x); af[1] = (short)f2bf(a0.y);
        af[2] = (short)f2bf(a0.z); af[3] = (short)f2bf(a0.w);
        af[4] = (short)f2bf(a1.x); af[5] = (short)f2bf(a1.y);
        af[6] = (short)f2bf(a1.z); af[7] = (short)f2bf(a1.w);
        if (!inb) af = (short8)0;

        // prefetch next slice of x
        if (ks < 7 && inb) {
            int kn = (ks + 1) * 32 + k0q;
            a0 = *(const float4*)&x[(long long)arow * F_IN + kn];
            a1 = *(const float4*)&x[(long long)arow * F_IN + kn + 4];
        }

        // B fragments direct from L2-resident Wt:
        // short8 index (n*4 + quad) within the ks-slice (n = t*16 + m16)
        const short8* wrow = (const short8*)(Wt + (size_t)ks * F_OUT * 32);
        #pragma unroll
        for (int t = 0; t < 8; ++t) {
            short8 bf = wrow[(t * 16 + m16) * 4 + quad];
            acc[t] = __builtin_amdgcn_mfma_f32_16x16x32_bf16(af, bf, acc[t], 0, 0, 0);
        }
    }

    // D layout: col = lane&15, row = quad*4 + reg
    const int rbase = blockIdx.x * 64 + wave * 16 + quad * 4;
    #pragma unroll
    for (int r = 0; r < 4; ++r) {
        int grow = rbase + r;
        if (grow < n_nodes) {
            #pragma unroll
            for (int t = 0; t < 8; ++t)
                h[(long long)grow * F_OUT + t * 16 + m16] = f2bf(acc[t][r]);
        }
    }
}

// ---------------------------------------------------------------------------
// Pass A: 196-way split by super-bucket (dst>>9) into FIXED CAPS segments.
// LDS-ranked batch scatter. Packing: x = src | (dst&511)<<17.
// ---------------------------------------------------------------------------
__global__ __launch_bounds__(256) void partition_a_kernel(
    const int* __restrict__ src, const int* __restrict__ dst,
    const float* __restrict__ vals, int* __restrict__ cursorA,
    uint2* __restrict__ payA, int n_edges)
{
    __shared__ int hist[256];
    __shared__ int base[256];
    const int tid = threadIdx.x;
    const int i0  = blockIdx.x * BATCH;

    hist[tid] = 0;
    __syncthreads();

    uint2 p[EPT];
    int   sb[EPT];
    int   rk[EPT];
    #pragma unroll
    for (int j = 0; j < EPT; ++j) {
        int i = i0 + j * 256 + tid;
        sb[j] = -1;
        if (i < n_edges) {
            int d = dst[i];
            p[j] = make_uint2((unsigned)src[i] | ((unsigned)(d & (NPS - 1)) << 17),
                              __float_as_uint(vals[i]));
            sb[j] = d >> NPSH;
            rk[j] = atomicAdd(&hist[sb[j]], 1);
        }
    }
    __syncthreads();
    { int v = hist[tid]; if (v) base[tid] = atomicAdd(&cursorA[tid], v); }
    __syncthreads();
    #pragma unroll
    for (int j = 0; j < EPT; ++j)
        if (sb[j] >= 0) payA[base[sb[j]] + rk[j]] = p[j];
}

// ---------------------------------------------------------------------------
// Sort within super-bucket: one block per super (196 blocks, 512 threads).
// Per-node LDS histogram (512 bins) -> scan -> offsets -> scatter.
// ---------------------------------------------------------------------------
__global__ __launch_bounds__(512) void sort_super_kernel(
    const uint2* __restrict__ payA, const int* __restrict__ super_end,
    uint2* __restrict__ sorted, int* __restrict__ offsets, int n_nodes)
{
    __shared__ int bins[NPS];
    __shared__ int bcur[NPS];
    __shared__ int ss[NPS];

    const int sp  = blockIdx.x;
    const int tid = threadIdx.x;
    const int lo  = sp * CAPS;
    const int hi  = super_end[sp];

    bins[tid] = 0;
    __syncthreads();

    {
        int e = lo + tid;
        for (; e + 3 * 512 < hi; e += 4 * 512) {
            unsigned x0 = payA[e].x, x1 = payA[e + 512].x,
                     x2 = payA[e + 1024].x, x3 = payA[e + 1536].x;
            atomicAdd(&bins[(x0 >> 17) & (NPS - 1)], 1);
            atomicAdd(&bins[(x1 >> 17) & (NPS - 1)], 1);
            atomicAdd(&bins[(x2 >> 17) & (NPS - 1)], 1);
            atomicAdd(&bins[(x3 >> 17) & (NPS - 1)], 1);
        }
        for (; e < hi; e += 512)
            atomicAdd(&bins[(payA[e].x >> 17) & (NPS - 1)], 1);
    }
    __syncthreads();

    // exclusive scan over 512 bins (1 bin/thread, Hillis-Steele)
    const int c0 = bins[tid];
    ss[tid] = c0;
    __syncthreads();
    for (int off = 1; off < 512; off <<= 1) {
        int v = (tid >= off) ? ss[tid - off] : 0;
        __syncthreads();
        ss[tid] += v;
        __syncthreads();
    }
    bcur[tid] = lo + ss[tid] - c0;
    __syncthreads();

    const int node0 = sp << NPSH;
    {
        int nd = node0 + tid;
        if (nd < n_nodes) offsets[nd] = bcur[tid];
    }
    __syncthreads();   // offsets reads of bcur complete before scatter mutates it

    {
        int e = lo + tid;
        for (; e + 3 * 512 < hi; e += 4 * 512) {
            uint2 p0 = payA[e], p1 = payA[e + 512], p2 = payA[e + 1024], p3 = payA[e + 1536];
            int q0 = atomicAdd(&bcur[(p0.x >> 17) & (NPS - 1)], 1);
            int q1 = atomicAdd(&bcur[(p1.x >> 17) & (NPS - 1)], 1);
            int q2 = atomicAdd(&bcur[(p2.x >> 17) & (NPS - 1)], 1);
            int q3 = atomicAdd(&bcur[(p3.x >> 17) & (NPS - 1)], 1);
            sorted[q0] = make_uint2(p0.x & 0x1FFFFu, p0.y);
            sorted[q1] = make_uint2(p1.x & 0x1FFFFu, p1.y);
            sorted[q2] = make_uint2(p2.x & 0x1FFFFu, p2.y);
            sorted[q3] = make_uint2(p3.x & 0x1FFFFu, p3.y);
        }
        for (; e < hi; e += 512) {
            uint2 p = payA[e];
            int q = atomicAdd(&bcur[(p.x >> 17) & (NPS - 1)], 1);
            sorted[q] = make_uint2(p.x & 0x1FFFFu, p.y);
        }
    }
}

// ---------------------------------------------------------------------------
// Gather: one wave per dst node, unroll-16, plain loads (proven 102-105us;
// at the measured 2.3 TB/s L2-miss-path wall). Segment-aware end.
// ---------------------------------------------------------------------------
__global__ __launch_bounds__(256) void gather_kernel(
    const unsigned short* __restrict__ h, const int* __restrict__ offsets,
    const uint2* __restrict__ sv, const int* __restrict__ super_end,
    const float* __restrict__ bias, float* __restrict__ out, int n_nodes)
{
    int node = blockIdx.x * 4 + (threadIdx.x >> 6);
    if (node >= n_nodes) return;
    int lane = threadIdx.x & 63;
    int f = lane * 2;

    int start = offsets[node];
    int nxt   = node + 1;
    int end   = (nxt == n_nodes || (nxt & (NPS - 1)) == 0)
              ? super_end[node >> NPSH] : offsets[nxt];

    float ax = 0.f, ay = 0.f;

    for (int e = start; e < end; e += 16) {
        uint2 p[16];
        #pragma unroll
        for (int j = 0; j < 16; ++j) {
            int ei = (e + j < end) ? e + j : end - 1;
            p[j] = sv[ei];
        }
        unsigned u[16];
        #pragma unroll
        for (int j = 0; j < 16; ++j)
            u[j] = *(const unsigned*)&h[(size_t)(p[j].x & 0x00FFFFFFu) * F_OUT + f];
        #pragma unroll
        for (int j = 0; j < 16; ++j) {
            float v = (e + j < end) ? __uint_as_float(p[j].y) : 0.f;
            ax += v * __uint_as_float(u[j] << 16);
            ay += v * __uint_as_float(u[j] & 0xffff0000u);
        }
    }

    float2 b = *(const float2*)&bias[f];
    *(float2*)&out[(size_t)node * F_OUT + f] = make_float2(ax + b.x, ay + b.y);
}

// ---------------------------------------------------------------------------
extern "C" void kernel_launch(void* const* d_in, const int* in_sizes, int n_in,
                              void* d_out, int out_size, void* d_ws, size_t ws_size,
                              hipStream_t stream)
{
    const float* x     = (const float*)d_in[0];
    const int*   esrc  = (const int*)d_in[1];
    const int*   edst  = (const int*)d_in[2];
    const float* evals = (const float*)d_in[3];
    const float* W     = (const float*)d_in[4];
    const float* bias  = (const float*)d_in[5];
    float*       out   = (float*)d_out;

    const int n_nodes = in_sizes[0] / F_IN;
    const int n_edges = in_sizes[1];
    const int nsup    = (n_nodes + NPS - 1) >> NPSH;   // 196

    auto align16 = [](size_t v) { return (v + 15) & ~(size_t)15; };
    char*  base = (char*)d_ws;
    size_t off  = 0;
    unsigned short* h  = (unsigned short*)(base + off); off = align16(off + (size_t)n_nodes * F_OUT * 2);
    unsigned short* Wt = (unsigned short*)(base + off); off = align16(off + (size_t)F_IN * F_OUT * 2);
    int*   cursorA     = (int*)(base + off);   off = align16(off + (size_t)256 * 4);
    int*   offsets     = (int*)(base + off);   off = align16(off + (size_t)n_nodes * 4);
    uint2* payA        = (uint2*)(base + off); off = align16(off + (size_t)nsup * CAPS * 8);
    uint2* sorted      = (uint2*)(base + off); off = align16(off + (size_t)nsup * CAPS * 8);
    (void)ws_size;

    // 1) dense transform (+ seed segment cursors)
    prep_wt_kernel<<<F_OUT, F_IN, 0, stream>>>(W, Wt, cursorA);
    gemm_mfma_kernel<<<(n_nodes + 63) / 64, 256, 0, stream>>>(x, Wt, h, n_nodes);

    // 2) segmented append partition (196-way), then per-super sort -> CSR
    partition_a_kernel<<<(n_edges + BATCH - 1) / BATCH, 256, 0, stream>>>(
        esrc, edst, evals, cursorA, payA, n_edges);
    sort_super_kernel<<<nsup, 512, 0, stream>>>(
        payA, cursorA, sorted, offsets, n_nodes);

    // 3) gather (bias fused), plain loads
    gather_kernel<<<(n_nodes + 3) / 4, 256, 0, stream>>>(
        h, offsets, sorted, cursorA, bias, out, n_nodes);
}

// Round 13
// 311.636 us; speedup vs baseline: 1.0855x; 1.0855x over previous
//
#include <hip/hip_runtime.h>

constexpr int F_IN  = 256;
constexpr int F_OUT = 128;

constexpr int NPSH  = 9;              // 512 nodes per super-bucket
constexpr int NPS   = 1 << NPSH;      // 512
constexpr int EPT   = 16;             // edges/thread in partition pass
constexpr int BATCH = 256 * EPT;      // 4096 edges per block batch
constexpr int CAPS  = 9216;           // slots per segment (avg 8192, +11 sigma)

typedef __attribute__((ext_vector_type(8))) short short8;
typedef __attribute__((ext_vector_type(4))) float f32x4;

// fp32 -> bf16 round-to-nearest-even
__device__ __forceinline__ unsigned short f2bf(float f) {
    unsigned u = __float_as_uint(f);
    u += 0x7fffu + ((u >> 16) & 1u);
    return (unsigned short)(u >> 16);
}

// ---------------------------------------------------------------------------
// Prep: Wt swizzled K-major. Seeds segmented append cursors cursorA[s]=s*CAPS.
// ---------------------------------------------------------------------------
__global__ void prep_wt_kernel(const float* __restrict__ W,
                               unsigned short* __restrict__ Wt,
                               int* __restrict__ cursorA)
{
    int n = blockIdx.x;      // 0..127
    int k = threadIdx.x;     // 0..255
    int ks = k >> 5, kk = k & 31;
    Wt[((ks * F_OUT) + n) * 32 + kk] = f2bf(W[k * F_OUT + n]);
    if (blockIdx.x == 0) cursorA[threadIdx.x] = threadIdx.x * CAPS;
}

// ---------------------------------------------------------------------------
// FUSED: gemm (blocks [0,ngemm)) + partition (blocks [ngemm, ngemm+npart)).
// The two phases touch disjoint data and have no ordering constraint; fusing
// removes one launch gap and lets partition's memory-bound blocks fill CUs
// as gemm blocks drain.
//   gemm path: R11-PROVEN LDS-staged MFMA (R12's LDS-free variant was -10us,
//   reverted). partition path: 196-way LDS-ranked segmented append.
// LDS footprint = union (10240 + 2048 B); both paths 256 threads.
// ---------------------------------------------------------------------------
#define BS_LD 40   // 32 + 8 pad shorts; 80B row stride, 16B aligned

__global__ __launch_bounds__(256) void fused_gemm_partition_kernel(
    const float* __restrict__ x, const unsigned short* __restrict__ Wt,
    unsigned short* __restrict__ h, int n_nodes, int ngemm,
    const int* __restrict__ src, const int* __restrict__ dst,
    const float* __restrict__ vals, int* __restrict__ cursorA,
    uint2* __restrict__ payA, int n_edges)
{
    __shared__ unsigned short Bs[F_OUT * BS_LD];   // 10240 B (gemm path)
    __shared__ int hist[256];                      // 1 KB (partition path)
    __shared__ int base[256];                      // 1 KB (partition path)

    const int tid = threadIdx.x;

    if ((int)blockIdx.x < ngemm) {
        // ----------------- gemm path -----------------
        const int wave = tid >> 6;
        const int lane = tid & 63;
        const int m16  = lane & 15;
        const int quad = lane >> 4;
        const int k0q  = quad * 8;
        const int arow = blockIdx.x * 64 + wave * 16 + m16;
        const bool inb = arow < n_nodes;

        f32x4 acc[8];
        #pragma unroll
        for (int t = 0; t < 8; ++t) acc[t] = (f32x4)(0.f);

        float4 a0 = make_float4(0.f,0.f,0.f,0.f), a1 = a0;
        if (inb) {
            a0 = *(const float4*)&x[(long long)arow * F_IN + k0q];
            a1 = *(const float4*)&x[(long long)arow * F_IN + k0q + 4];
        }

        for (int ks = 0; ks < 8; ++ks) {
            const uint4* wsrc = (const uint4*)(Wt + (size_t)ks * F_OUT * 32);
            #pragma unroll
            for (int p = 0; p < 2; ++p) {
                int c   = p * 256 + tid;
                int row = c >> 2;
                int o16 = c & 3;
                *(uint4*)&Bs[row * BS_LD + o16 * 8] = wsrc[c];
            }
            __syncthreads();

            short8 af;
            af[0] = (short)f2bf(a0.x); af[1] = (short)f2bf(a0.y);
            af[2] = (short)f2bf(a0.z); af[3] = (short)f2bf(a0.w);
            af[4] = (short)f2bf(a1.x); af[5] = (short)f2bf(a1.y);
            af[6] = (short)f2bf(a1.z); af[7] = (short)f2bf(a1.w);
            if (!inb) af = (short8)0;

            if (ks < 7 && inb) {
                int kn = (ks + 1) * 32 + k0q;
                a0 = *(const float4*)&x[(long long)arow * F_IN + kn];
                a1 = *(const float4*)&x[(long long)arow * F_IN + kn + 4];
            }

            #pragma unroll
            for (int t = 0; t < 8; ++t) {
                int n = t * 16 + m16;
                short8 bf = *(const short8*)&Bs[n * BS_LD + k0q];
                acc[t] = __builtin_amdgcn_mfma_f32_16x16x32_bf16(af, bf, acc[t], 0, 0, 0);
            }
            __syncthreads();
        }

        const int rbase = blockIdx.x * 64 + wave * 16 + quad * 4;
        #pragma unroll
        for (int r = 0; r < 4; ++r) {
            int grow = rbase + r;
            if (grow < n_nodes) {
                #pragma unroll
                for (int t = 0; t < 8; ++t)
                    h[(long long)grow * F_OUT + t * 16 + m16] = f2bf(acc[t][r]);
            }
        }
    } else {
        // ----------------- partition path -----------------
        const int i0 = (blockIdx.x - ngemm) * BATCH;

        hist[tid] = 0;
        __syncthreads();

        uint2 p[EPT];
        int   sb[EPT];
        int   rk[EPT];
        #pragma unroll
        for (int j = 0; j < EPT; ++j) {
            int i = i0 + j * 256 + tid;
            sb[j] = -1;
            if (i < n_edges) {
                int d = dst[i];
                p[j] = make_uint2((unsigned)src[i] | ((unsigned)(d & (NPS - 1)) << 17),
                                  __float_as_uint(vals[i]));
                sb[j] = d >> NPSH;
                rk[j] = atomicAdd(&hist[sb[j]], 1);
            }
        }
        __syncthreads();
        { int v = hist[tid]; if (v) base[tid] = atomicAdd(&cursorA[tid], v); }
        __syncthreads();
        #pragma unroll
        for (int j = 0; j < EPT; ++j)
            if (sb[j] >= 0) payA[base[sb[j]] + rk[j]] = p[j];
    }
}

// ---------------------------------------------------------------------------
// Sort within super-bucket: one block per super (196 blocks, 512 threads).
// Per-node LDS histogram (512 bins) -> scan -> offsets -> scatter.
// ---------------------------------------------------------------------------
__global__ __launch_bounds__(512) void sort_super_kernel(
    const uint2* __restrict__ payA, const int* __restrict__ super_end,
    uint2* __restrict__ sorted, int* __restrict__ offsets, int n_nodes)
{
    __shared__ int bins[NPS];
    __shared__ int bcur[NPS];
    __shared__ int ss[NPS];

    const int sp  = blockIdx.x;
    const int tid = threadIdx.x;
    const int lo  = sp * CAPS;
    const int hi  = super_end[sp];

    bins[tid] = 0;
    __syncthreads();

    {
        int e = lo + tid;
        for (; e + 3 * 512 < hi; e += 4 * 512) {
            unsigned x0 = payA[e].x, x1 = payA[e + 512].x,
                     x2 = payA[e + 1024].x, x3 = payA[e + 1536].x;
            atomicAdd(&bins[(x0 >> 17) & (NPS - 1)], 1);
            atomicAdd(&bins[(x1 >> 17) & (NPS - 1)], 1);
            atomicAdd(&bins[(x2 >> 17) & (NPS - 1)], 1);
            atomicAdd(&bins[(x3 >> 17) & (NPS - 1)], 1);
        }
        for (; e < hi; e += 512)
            atomicAdd(&bins[(payA[e].x >> 17) & (NPS - 1)], 1);
    }
    __syncthreads();

    // exclusive scan over 512 bins (1 bin/thread, Hillis-Steele)
    const int c0 = bins[tid];
    ss[tid] = c0;
    __syncthreads();
    for (int off = 1; off < 512; off <<= 1) {
        int v = (tid >= off) ? ss[tid - off] : 0;
        __syncthreads();
        ss[tid] += v;
        __syncthreads();
    }
    bcur[tid] = lo + ss[tid] - c0;
    __syncthreads();

    const int node0 = sp << NPSH;
    {
        int nd = node0 + tid;
        if (nd < n_nodes) offsets[nd] = bcur[tid];
    }
    __syncthreads();   // offsets reads of bcur complete before scatter mutates it

    {
        int e = lo + tid;
        for (; e + 3 * 512 < hi; e += 4 * 512) {
            uint2 p0 = payA[e], p1 = payA[e + 512], p2 = payA[e + 1024], p3 = payA[e + 1536];
            int q0 = atomicAdd(&bcur[(p0.x >> 17) & (NPS - 1)], 1);
            int q1 = atomicAdd(&bcur[(p1.x >> 17) & (NPS - 1)], 1);
            int q2 = atomicAdd(&bcur[(p2.x >> 17) & (NPS - 1)], 1);
            int q3 = atomicAdd(&bcur[(p3.x >> 17) & (NPS - 1)], 1);
            sorted[q0] = make_uint2(p0.x & 0x1FFFFu, p0.y);
            sorted[q1] = make_uint2(p1.x & 0x1FFFFu, p1.y);
            sorted[q2] = make_uint2(p2.x & 0x1FFFFu, p2.y);
            sorted[q3] = make_uint2(p3.x & 0x1FFFFu, p3.y);
        }
        for (; e < hi; e += 512) {
            uint2 p = payA[e];
            int q = atomicAdd(&bcur[(p.x >> 17) & (NPS - 1)], 1);
            sorted[q] = make_uint2(p.x & 0x1FFFFu, p.y);
        }
    }
}

// ---------------------------------------------------------------------------
// Gather: one wave per dst node, unroll-16, plain loads (proven 102-105us;
// at the measured 2.3 TB/s L2-miss-path wall). Segment-aware end.
// ---------------------------------------------------------------------------
__global__ __launch_bounds__(256) void gather_kernel(
    const unsigned short* __restrict__ h, const int* __restrict__ offsets,
    const uint2* __restrict__ sv, const int* __restrict__ super_end,
    const float* __restrict__ bias, float* __restrict__ out, int n_nodes)
{
    int node = blockIdx.x * 4 + (threadIdx.x >> 6);
    if (node >= n_nodes) return;
    int lane = threadIdx.x & 63;
    int f = lane * 2;

    int start = offsets[node];
    int nxt   = node + 1;
    int end   = (nxt == n_nodes || (nxt & (NPS - 1)) == 0)
              ? super_end[node >> NPSH] : offsets[nxt];

    float ax = 0.f, ay = 0.f;

    for (int e = start; e < end; e += 16) {
        uint2 p[16];
        #pragma unroll
        for (int j = 0; j < 16; ++j) {
            int ei = (e + j < end) ? e + j : end - 1;
            p[j] = sv[ei];
        }
        unsigned u[16];
        #pragma unroll
        for (int j = 0; j < 16; ++j)
            u[j] = *(const unsigned*)&h[(size_t)(p[j].x & 0x00FFFFFFu) * F_OUT + f];
        #pragma unroll
        for (int j = 0; j < 16; ++j) {
            float v = (e + j < end) ? __uint_as_float(p[j].y) : 0.f;
            ax += v * __uint_as_float(u[j] << 16);
            ay += v * __uint_as_float(u[j] & 0xffff0000u);
        }
    }

    float2 b = *(const float2*)&bias[f];
    *(float2*)&out[(size_t)node * F_OUT + f] = make_float2(ax + b.x, ay + b.y);
}

// ---------------------------------------------------------------------------
extern "C" void kernel_launch(void* const* d_in, const int* in_sizes, int n_in,
                              void* d_out, int out_size, void* d_ws, size_t ws_size,
                              hipStream_t stream)
{
    const float* x     = (const float*)d_in[0];
    const int*   esrc  = (const int*)d_in[1];
    const int*   edst  = (const int*)d_in[2];
    const float* evals = (const float*)d_in[3];
    const float* W     = (const float*)d_in[4];
    const float* bias  = (const float*)d_in[5];
    float*       out   = (float*)d_out;

    const int n_nodes = in_sizes[0] / F_IN;
    const int n_edges = in_sizes[1];
    const int nsup    = (n_nodes + NPS - 1) >> NPSH;        // 196
    const int ngemm   = (n_nodes + 63) / 64;                // 1563
    const int npart   = (n_edges + BATCH - 1) / BATCH;      // 391

    auto align16 = [](size_t v) { return (v + 15) & ~(size_t)15; };
    char*  base = (char*)d_ws;
    size_t off  = 0;
    unsigned short* h  = (unsigned short*)(base + off); off = align16(off + (size_t)n_nodes * F_OUT * 2);
    unsigned short* Wt = (unsigned short*)(base + off); off = align16(off + (size_t)F_IN * F_OUT * 2);
    int*   cursorA     = (int*)(base + off);   off = align16(off + (size_t)256 * 4);
    int*   offsets     = (int*)(base + off);   off = align16(off + (size_t)n_nodes * 4);
    uint2* payA        = (uint2*)(base + off); off = align16(off + (size_t)nsup * CAPS * 8);
    uint2* sorted      = (uint2*)(base + off); off = align16(off + (size_t)nsup * CAPS * 8);
    (void)ws_size;

    // 1) Wt swizzle + cursor seed
    prep_wt_kernel<<<F_OUT, F_IN, 0, stream>>>(W, Wt, cursorA);

    // 2) fused: gemm (1563 blocks) + segmented-append partition (391 blocks)
    fused_gemm_partition_kernel<<<ngemm + npart, 256, 0, stream>>>(
        x, Wt, h, n_nodes, ngemm, esrc, edst, evals, cursorA, payA, n_edges);

    // 3) per-super sort -> CSR
    sort_super_kernel<<<nsup, 512, 0, stream>>>(
        payA, cursorA, sorted, offsets, n_nodes);

    // 4) gather (bias fused)
    gather_kernel<<<(n_nodes + 3) / 4, 256, 0, stream>>>(
        h, offsets, sorted, cursorA, bias, out, n_nodes);
}